// Round 11
// baseline (133.842 us; speedup 1.0000x reference)
//
#include <hip/hip_runtime.h>
#include <hip/hip_bf16.h>
#include <math.h>

// bucket = 64 consecutive dst nodes. key packs (dlow<<17 | src), valid for n < 131072.
#define BSHIFT 6
#define BNODES 64
#define MAXB 1024   // max buckets supported by the fused bucket scan (n <= 65536)
#define SORTCAP 4096

// ---------------- inline dtype detection: int64 vs int32 edge_index ----------------
__device__ __forceinline__ bool detect_f64(const void* edges, long long nn) {
    const long long* e64 = (const long long*)edges;
    bool ok = true;
#pragma unroll
    for (int i = 0; i < 8; ++i) {
        long long v = e64[i];
        ok = ok && (v >= 0 && v < nn);
    }
    return ok;
}

__device__ __forceinline__ float bf16lo(unsigned int u) {
    return __uint_as_float(u << 16);
}
__device__ __forceinline__ float bf16hi(unsigned int u) {
    return __uint_as_float(u & 0xFFFF0000u);
}
__device__ __forceinline__ float bf16dec(unsigned short u) {
    return __uint_as_float(((unsigned int)u) << 16);
}
__device__ __forceinline__ unsigned short bf16enc(float f) {
    __hip_bfloat16 h = __float2bfloat16(f);
    return *reinterpret_cast<unsigned short*>(&h);
}

// ---- (A) per-block-slice histogram -> partial[b*nblk + i] (plain stores) ----
__global__ __launch_bounds__(512) void k_hist(const void* edges, long long nn,
                                              long long E, long long epb,
                                              int nbuckets, int nblk, int* partial) {
    __shared__ int cnt[MAXB];
    int t = threadIdx.x;
    int i = blockIdx.x;
    for (int b = t; b < nbuckets; b += 512) cnt[b] = 0;
    __syncthreads();
    bool f64 = detect_f64(edges, nn);
    long long e0 = (long long)i * epb;
    long long e1 = e0 + epb; if (e1 > E) e1 = E;
    for (long long e = e0 + t; e < e1; e += 512) {
        int d = f64 ? (int)((const long long*)edges)[E + e] : ((const int*)edges)[E + e];
        atomicAdd(&cnt[d >> BSHIFT], 1);
    }
    __syncthreads();
    for (int b = t; b < nbuckets; b += 512) partial[b * nblk + i] = cnt[b];
}

// ---- (B) per-bucket exclusive scan over blocks + fused bucket-level scan ----
// One block per bucket scans partial[b][*] -> totals[b]; the last block to
// finish (single ticket atomic per block) then scans totals -> base.
__global__ __launch_bounds__(256) void k_scanB(int* partial, int nblk, int nbuckets,
                                               int* totals, int* base, int* ticket) {
    __shared__ int tmp[256];
    __shared__ int lastflag;
    int b = blockIdx.x, t = threadIdx.x;
    int v = (t < nblk) ? partial[b * nblk + t] : 0;
    tmp[t] = v;
    __syncthreads();
    for (int off = 1; off < 256; off <<= 1) {
        int a = (t >= off) ? tmp[t - off] : 0;
        __syncthreads();
        tmp[t] += a;
        __syncthreads();
    }
    if (t < nblk) partial[b * nblk + t] = tmp[t] - v;  // exclusive over blocks
    if (t == 255) {
        totals[b] = tmp[255];
        __threadfence();
        int r = atomicAdd(ticket, 1);
        lastflag = (r == (int)gridDim.x - 1);
    }
    __syncthreads();
    if (!lastflag) return;
    // last block: exclusive scan of totals[0..nbuckets) -> base (4 elems/thread)
    int i0 = t * 4;
    int x0 = (i0 + 0 < nbuckets) ? atomicAdd(&totals[i0 + 0], 0) : 0;  // coherent reads
    int x1 = (i0 + 1 < nbuckets) ? atomicAdd(&totals[i0 + 1], 0) : 0;
    int x2 = (i0 + 2 < nbuckets) ? atomicAdd(&totals[i0 + 2], 0) : 0;
    int x3 = (i0 + 3 < nbuckets) ? atomicAdd(&totals[i0 + 3], 0) : 0;
    int s4 = x0 + x1 + x2 + x3;
    __syncthreads();
    tmp[t] = s4;
    __syncthreads();
    for (int off = 1; off < 256; off <<= 1) {
        int a = (t >= off) ? tmp[t - off] : 0;
        __syncthreads();
        tmp[t] += a;
        __syncthreads();
    }
    int ex = tmp[t] - s4;
    if (i0 + 0 < nbuckets) base[i0 + 0] = ex;
    if (i0 + 1 < nbuckets) base[i0 + 1] = ex + x0;
    if (i0 + 2 < nbuckets) base[i0 + 2] = ex + x0 + x1;
    if (i0 + 3 < nbuckets) base[i0 + 3] = ex + x0 + x1 + x2;
}

// ---- (D) place keys: LDS cursors seeded from base+partial; no global atomics ----
__global__ __launch_bounds__(512) void k_place(const void* edges, long long nn,
                                               long long E, long long epb,
                                               int nbuckets, int nblk,
                                               const int* __restrict__ base,
                                               const int* __restrict__ partial,
                                               unsigned int* keys) {
    __shared__ int cur[MAXB];
    int t = threadIdx.x;
    int i = blockIdx.x;
    for (int b = t; b < nbuckets; b += 512) cur[b] = base[b] + partial[b * nblk + i];
    __syncthreads();
    bool f64 = detect_f64(edges, nn);
    long long e0 = (long long)i * epb;
    long long e1 = e0 + epb; if (e1 > E) e1 = E;
    for (long long e = e0 + t; e < e1; e += 512) {
        int s, d;
        if (f64) {
            const long long* ee = (const long long*)edges;
            s = (int)ee[e]; d = (int)ee[E + e];
        } else {
            const int* ee = (const int*)edges;
            s = ee[e]; d = ee[E + e];
        }
        int pos = atomicAdd(&cur[d >> BSHIFT], 1);
        keys[pos] = (unsigned int)s | ((unsigned int)(d & (BNODES - 1)) << 17);
    }
}

// -------- per-bucket LDS counting sort -> node-exact CSR; fuses deg/dinv --------
__global__ __launch_bounds__(256) void k_sortdeg(unsigned int* keys,
                                                 const int* __restrict__ base,
                                                 const int* __restrict__ totals,
                                                 int* rowstart, int* counts,
                                                 float* dinv, int n,
                                                 unsigned int* scratch) {
    __shared__ unsigned int kbuf[SORTCAP];
    __shared__ int hist[BNODES];
    __shared__ int cur[BNODES];
    int t = threadIdx.x;
    int bk = blockIdx.x;
    int st = base[bk], c = totals[bk];
    if (t < BNODES) hist[t] = 0;
    __syncthreads();
    bool fits = (c <= SORTCAP);
    if (fits) {
        for (int i = t; i < c; i += 256) {
            unsigned int k = keys[st + i];
            kbuf[i] = k;
            atomicAdd(&hist[k >> 17], 1);
        }
    } else {  // statistically never for random edges; correct fallback via global scratch
        for (int i = t; i < c; i += 256) {
            unsigned int k = keys[st + i];
            scratch[st + i] = k;
            atomicAdd(&hist[k >> 17], 1);
        }
    }
    __syncthreads();
    if (t < 64) {  // wave 0: scan 64 counters
        int v = hist[t];
        int incl = v;
        for (int o = 1; o < 64; o <<= 1) {
            int other = __shfl_up(incl, o, 64);
            if (t >= o) incl += other;
        }
        int ex = incl - v;
        cur[t] = ex;
        int node = bk * BNODES + t;
        if (node < n) {
            rowstart[node] = st + ex;
            counts[node] = v;
            dinv[node] = rsqrtf((float)v + 1.0f);
        }
    }
    __syncthreads();
    if (fits) {
        for (int i = t; i < c; i += 256) {
            unsigned int k = kbuf[i];
            int pos = atomicAdd(&cur[k >> 17], 1);
            keys[st + pos] = k & 0x1FFFFu;
        }
    } else {
        for (int i = t; i < c; i += 256) {
            unsigned int k = scratch[st + i];
            int pos = atomicAdd(&cur[k >> 17], 1);
            keys[st + pos] = k & 0x1FFFFu;
        }
    }
}

// -------- GEMM1: h1b[n,64](bf16) = dinv * (x[n,64] @ W1[64,64]) --------
__global__ __launch_bounds__(256) void k_gemm1(const float* __restrict__ x,
                                               const float* __restrict__ W,
                                               const float* __restrict__ dinv,
                                               unsigned short* __restrict__ h) {
    __shared__ float Ws[64][64];
    __shared__ float xs[16][64];
    int t = threadIdx.x;
    for (int i = t; i < 64 * 64; i += 256) Ws[i >> 6][i & 63] = W[i];
    long long row0 = (long long)blockIdx.x * 16;
    ((float4*)xs)[t] = ((const float4*)(x + row0 * 64))[t];
    __syncthreads();
    int r = t >> 4, c0 = (t & 15) * 4;
    float4 acc = {0.f, 0.f, 0.f, 0.f};
#pragma unroll
    for (int k = 0; k < 64; ++k) {
        float xv = xs[r][k];
        float4 wv = *((const float4*)&Ws[k][c0]);
        acc.x += xv * wv.x; acc.y += xv * wv.y;
        acc.z += xv * wv.z; acc.w += xv * wv.w;
    }
    float di = dinv[row0 + r];
    ushort4 pk;
    pk.x = bf16enc(di * acc.x);
    pk.y = bf16enc(di * acc.y);
    pk.z = bf16enc(di * acc.z);
    pk.w = bf16enc(di * acc.w);
    *((ushort4*)(h + (row0 + r) * 64 + c0)) = pk;
}

// ------- GEMM2: h2b[n,16](bf16) = dinv * (out1b[n,64](bf16) @ W2[64,16]) -------
__global__ __launch_bounds__(256) void k_gemm2(const unsigned short* __restrict__ h,
                                               const float* __restrict__ W,
                                               const float* __restrict__ dinv,
                                               unsigned short* __restrict__ h2) {
    __shared__ float Ws[64 * 16];
    __shared__ float xs[16][64];
    int t = threadIdx.x;
    for (int i = t; i < 64 * 16; i += 256) Ws[i] = W[i];
    long long row0 = (long long)blockIdx.x * 16;
    ushort4 u4 = ((const ushort4*)(h + row0 * 64))[t];
    int lr = t >> 4, lc = (t & 15) * 4;
    xs[lr][lc + 0] = bf16dec(u4.x);
    xs[lr][lc + 1] = bf16dec(u4.y);
    xs[lr][lc + 2] = bf16dec(u4.z);
    xs[lr][lc + 3] = bf16dec(u4.w);
    __syncthreads();
    int r = t >> 4, c = t & 15;
    float acc = 0.f;
#pragma unroll
    for (int k = 0; k < 64; ++k) acc += xs[r][k] * Ws[k * 16 + c];
    h2[(row0 + r) * 16 + c] = bf16enc(dinv[row0 + r] * acc);
}

// ------- CSR aggregation, 64 feats (bf16, 8-wide): wave per node ----------------
// 8 lanes x uint4 (16B) cover a 128B row; 8 edge-groups -> 8 random lines per
// load instruction, 16 edges in flight with the x2 unroll.
#define ACC8(u) do { \
    a0 += bf16lo((u).x); a1 += bf16hi((u).x); \
    a2 += bf16lo((u).y); a3 += bf16hi((u).y); \
    a4 += bf16lo((u).z); a5 += bf16hi((u).z); \
    a6 += bf16lo((u).w); a7 += bf16hi((u).w); } while (0)

__global__ __launch_bounds__(256) void k_agg64(const int* __restrict__ rowstart,
                                               const int* __restrict__ counts,
                                               const unsigned int* __restrict__ srcs,
                                               const uint4* __restrict__ hb8,
                                               const float* __restrict__ dinv,
                                               const float* __restrict__ b,
                                               unsigned short* __restrict__ out, int n) {
    int d = (blockIdx.x * 256 + threadIdx.x) >> 6;
    if (d >= n) return;
    int lane = threadIdx.x & 63;
    int g8 = lane >> 3;       // edge-group 0..7
    int fq = lane & 7;        // feature octet: feats 8fq..8fq+7
    float a0 = 0.f, a1 = 0.f, a2 = 0.f, a3 = 0.f;
    float a4 = 0.f, a5 = 0.f, a6 = 0.f, a7 = 0.f;
    if (g8 == 0) {            // self-loop counted once
        uint4 u = hb8[(long long)d * 8 + fq];
        ACC8(u);
    }
    int start = rowstart[d];
    int cnt = counts[d];
    int k = 0;
    for (; k + 16 <= cnt; k += 16) {
        unsigned int s0 = srcs[start + k + g8];
        unsigned int s1 = srcs[start + k + 8 + g8];
        uint4 u0 = hb8[(long long)s0 * 8 + fq];
        uint4 u1 = hb8[(long long)s1 * 8 + fq];
        ACC8(u0);
        ACC8(u1);
    }
    for (; k + 8 <= cnt; k += 8) {
        unsigned int s0 = srcs[start + k + g8];
        uint4 u0 = hb8[(long long)s0 * 8 + fq];
        ACC8(u0);
    }
    if (k + g8 < cnt) {
        unsigned int s0 = srcs[start + k + g8];
        uint4 u0 = hb8[(long long)s0 * 8 + fq];
        ACC8(u0);
    }
    // reduce across the 8 edge-groups (lanes with equal fq: xor 8,16,32)
    a0 += __shfl_xor(a0, 8); a0 += __shfl_xor(a0, 16); a0 += __shfl_xor(a0, 32);
    a1 += __shfl_xor(a1, 8); a1 += __shfl_xor(a1, 16); a1 += __shfl_xor(a1, 32);
    a2 += __shfl_xor(a2, 8); a2 += __shfl_xor(a2, 16); a2 += __shfl_xor(a2, 32);
    a3 += __shfl_xor(a3, 8); a3 += __shfl_xor(a3, 16); a3 += __shfl_xor(a3, 32);
    a4 += __shfl_xor(a4, 8); a4 += __shfl_xor(a4, 16); a4 += __shfl_xor(a4, 32);
    a5 += __shfl_xor(a5, 8); a5 += __shfl_xor(a5, 16); a5 += __shfl_xor(a5, 32);
    a6 += __shfl_xor(a6, 8); a6 += __shfl_xor(a6, 16); a6 += __shfl_xor(a6, 32);
    a7 += __shfl_xor(a7, 8); a7 += __shfl_xor(a7, 16); a7 += __shfl_xor(a7, 32);
    if (g8 == 0) {
        float di = dinv[d];
        float4 b0 = ((const float4*)b)[2 * fq];
        float4 b1 = ((const float4*)b)[2 * fq + 1];
        float o0 = fmaxf(di * a0 + b0.x, 0.f);
        float o1 = fmaxf(di * a1 + b0.y, 0.f);
        float o2 = fmaxf(di * a2 + b0.z, 0.f);
        float o3 = fmaxf(di * a3 + b0.w, 0.f);
        float o4 = fmaxf(di * a4 + b1.x, 0.f);
        float o5 = fmaxf(di * a5 + b1.y, 0.f);
        float o6 = fmaxf(di * a6 + b1.z, 0.f);
        float o7 = fmaxf(di * a7 + b1.w, 0.f);
        uint4 pk;
        pk.x = (unsigned int)bf16enc(o0) | ((unsigned int)bf16enc(o1) << 16);
        pk.y = (unsigned int)bf16enc(o2) | ((unsigned int)bf16enc(o3) << 16);
        pk.z = (unsigned int)bf16enc(o4) | ((unsigned int)bf16enc(o5) << 16);
        pk.w = (unsigned int)bf16enc(o6) | ((unsigned int)bf16enc(o7) << 16);
        ((uint4*)(out + (long long)d * 64))[fq] = pk;
    }
}

// ------- CSR aggregation, 16 feats (bf16, 4-wide) + fused log_softmax -----------
// 4 lanes x uint2 (8B) cover a 32B row; 4 edge-groups per 16-lane node group.
__global__ __launch_bounds__(256) void k_agg16(const int* __restrict__ rowstart,
                                               const int* __restrict__ counts,
                                               const unsigned int* __restrict__ srcs,
                                               const uint2* __restrict__ hb4,
                                               const float* __restrict__ dinv,
                                               const float* __restrict__ b,
                                               float* __restrict__ out, int n) {
    int g = (blockIdx.x * 256 + threadIdx.x) >> 4;
    if (g >= n) return;
    int lane = threadIdx.x & 15;
    int eg = lane >> 2;       // edge-group 0..3
    int fp = lane & 3;        // feature quad: feats 4fp..4fp+3
    float a0 = 0.f, a1 = 0.f, a2 = 0.f, a3 = 0.f;
    if (eg == 0) {
        uint2 u = hb4[(long long)g * 4 + fp];
        a0 = bf16lo(u.x); a1 = bf16hi(u.x); a2 = bf16lo(u.y); a3 = bf16hi(u.y);
    }
    int start = rowstart[g];
    int cnt = counts[g];
    int k = 0;
    for (; k + 8 <= cnt; k += 8) {
        unsigned int s0 = srcs[start + k + eg];
        unsigned int s1 = srcs[start + k + 4 + eg];
        uint2 u0 = hb4[(long long)s0 * 4 + fp];
        uint2 u1 = hb4[(long long)s1 * 4 + fp];
        a0 += bf16lo(u0.x); a1 += bf16hi(u0.x); a2 += bf16lo(u0.y); a3 += bf16hi(u0.y);
        a0 += bf16lo(u1.x); a1 += bf16hi(u1.x); a2 += bf16lo(u1.y); a3 += bf16hi(u1.y);
    }
    for (; k + 4 <= cnt; k += 4) {
        unsigned int s0 = srcs[start + k + eg];
        uint2 u0 = hb4[(long long)s0 * 4 + fp];
        a0 += bf16lo(u0.x); a1 += bf16hi(u0.x); a2 += bf16lo(u0.y); a3 += bf16hi(u0.y);
    }
    if (k + eg < cnt) {
        unsigned int s0 = srcs[start + k + eg];
        uint2 u0 = hb4[(long long)s0 * 4 + fp];
        a0 += bf16lo(u0.x); a1 += bf16hi(u0.x); a2 += bf16lo(u0.y); a3 += bf16hi(u0.y);
    }
    // reduce across the 4 edge-groups (xor 4, 8 within the 16-lane group)
    a0 += __shfl_xor(a0, 4); a0 += __shfl_xor(a0, 8);
    a1 += __shfl_xor(a1, 4); a1 += __shfl_xor(a1, 8);
    a2 += __shfl_xor(a2, 4); a2 += __shfl_xor(a2, 8);
    a3 += __shfl_xor(a3, 4); a3 += __shfl_xor(a3, 8);
    float di = dinv[g];
    float4 bb = ((const float4*)b)[fp];
    float v0 = di * a0 + bb.x;
    float v1 = di * a1 + bb.y;
    float v2 = di * a2 + bb.z;
    float v3 = di * a3 + bb.w;
    // softmax across the 16 features (4 per lane x 4 fp-lanes: xor 1, 2)
    float m = fmaxf(fmaxf(v0, v1), fmaxf(v2, v3));
    m = fmaxf(m, __shfl_xor(m, 1));
    m = fmaxf(m, __shfl_xor(m, 2));
    float ex = __expf(v0 - m) + __expf(v1 - m) + __expf(v2 - m) + __expf(v3 - m);
    ex += __shfl_xor(ex, 1);
    ex += __shfl_xor(ex, 2);
    float lse = __logf(ex) + m;
    if (eg == 0) {
        float4 o4;
        o4.x = v0 - lse; o4.y = v1 - lse; o4.z = v2 - lse; o4.w = v3 - lse;
        ((float4*)(out + (long long)g * 16))[fp] = o4;
    }
}

extern "C" void kernel_launch(void* const* d_in, const int* in_sizes, int n_in,
                              void* d_out, int out_size, void* d_ws, size_t ws_size,
                              hipStream_t stream) {
    const float* x  = (const float*)d_in[0];
    const void*  ei = d_in[1];
    const float* W1 = (const float*)d_in[2];
    const float* b1 = (const float*)d_in[3];
    const float* W2 = (const float*)d_in[4];
    const float* b2 = (const float*)d_in[5];

    long long dh  = in_sizes[3];                 // 64
    long long din = in_sizes[2] / dh;            // 64
    long long n   = in_sizes[0] / din;           // 50000
    long long E   = (long long)in_sizes[1] / 2;  // 1.6M
    int nbuckets  = (int)((n + BNODES - 1) >> BSHIFT);  // 782

    // slice size: 512 threads x ~16 edges; keep block count <= 256 (k_scanB width)
    long long epb = 8192;
    while ((E + epb - 1) / epb > 256) epb <<= 1;
    int nblk = (int)((E + epb - 1) / epb);       // 196 for E=1.6M

    char* ws = (char*)d_ws;
    auto alloc = [&](size_t bytes) { void* p = ws; ws += (bytes + 255) & ~255ULL; return p; };
    int*   ticket   = (int*)alloc(4);
    int*   totals   = (int*)alloc(nbuckets * 4);
    int*   base     = (int*)alloc(nbuckets * 4);
    int*   rowstart = (int*)alloc(n * 4);
    int*   counts   = (int*)alloc(n * 4);
    float* dinv     = (float*)alloc(n * 4);
    int*   partial  = (int*)alloc((size_t)nbuckets * nblk * 4);
    unsigned int* keys = (unsigned int*)alloc(E * 4);
    unsigned short* h1b  = (unsigned short*)alloc(n * 64 * 2);
    unsigned short* out1 = (unsigned short*)alloc(n * 64 * 2);
    unsigned short* h2b  = (unsigned short*)alloc(n * 16 * 2);
    // out1 written only after sortdeg completes; before then its space doubles
    // as the (statistically never used) big-bucket sort scratch (E*4 <= n*64*2).
    unsigned int* sort_scratch = (unsigned int*)out1;

    float* out = (float*)d_out;

    hipMemsetAsync(ticket, 0, 4, stream);

    // binning: hist -> fused block+bucket scan -> place (no contended global atomics)
    k_hist<<<nblk, 512, 0, stream>>>(ei, n, E, epb, nbuckets, nblk, partial);
    k_scanB<<<nbuckets, 256, 0, stream>>>(partial, nblk, nbuckets, totals, base, ticket);
    k_place<<<nblk, 512, 0, stream>>>(ei, n, E, epb, nbuckets, nblk, base, partial, keys);
    k_sortdeg<<<nbuckets, 256, 0, stream>>>(keys, base, totals, rowstart, counts,
                                            dinv, (int)n, sort_scratch);

    // layer 1
    k_gemm1<<<(int)(n / 16), 256, 0, stream>>>(x, W1, dinv, h1b);
    k_agg64<<<(int)((n * 64 + 255) / 256), 256, 0, stream>>>(
        rowstart, counts, keys, (const uint4*)h1b, dinv, b1, out1, (int)n);

    // layer 2
    k_gemm2<<<(int)(n / 16), 256, 0, stream>>>(out1, W2, dinv, h2b);
    k_agg16<<<(int)((n * 16 + 255) / 256), 256, 0, stream>>>(
        rowstart, counts, keys, (const uint2*)h2b, dinv, b2, out, (int)n);
}

// Round 12
// 118.040 us; speedup vs baseline: 1.1339x; 1.1339x over previous
//
#include <hip/hip_runtime.h>
#include <hip/hip_bf16.h>
#include <math.h>

// bucket = 64 consecutive dst nodes. key packs (dlow<<17 | src), valid for n < 131072.
#define BSHIFT 6
#define BNODES 64
#define MAXB 1024   // max buckets supported by single-block scan (n <= 65536)
#define SORTCAP 4096

// ---------------- inline dtype detection: int64 vs int32 edge_index ----------------
__device__ __forceinline__ bool detect_f64(const void* edges, long long nn) {
    const long long* e64 = (const long long*)edges;
    bool ok = true;
#pragma unroll
    for (int i = 0; i < 8; ++i) {
        long long v = e64[i];
        ok = ok && (v >= 0 && v < nn);
    }
    return ok;
}

__device__ __forceinline__ float bf16lo(unsigned int u) {
    return __uint_as_float(u << 16);
}
__device__ __forceinline__ float bf16hi(unsigned int u) {
    return __uint_as_float(u & 0xFFFF0000u);
}
__device__ __forceinline__ float bf16dec(unsigned short u) {
    return __uint_as_float(((unsigned int)u) << 16);
}
__device__ __forceinline__ unsigned short bf16enc(float f) {
    __hip_bfloat16 h = __float2bfloat16(f);
    return *reinterpret_cast<unsigned short*>(&h);
}

// ---- (A) per-block-slice histogram -> partial[b*nblk + i] (plain stores) ----
__global__ __launch_bounds__(512) void k_hist(const void* edges, long long nn,
                                              long long E, long long epb,
                                              int nbuckets, int nblk, int* partial) {
    __shared__ int cnt[MAXB];
    int t = threadIdx.x;
    int i = blockIdx.x;
    for (int b = t; b < nbuckets; b += 512) cnt[b] = 0;
    __syncthreads();
    bool f64 = detect_f64(edges, nn);
    long long e0 = (long long)i * epb;
    long long e1 = e0 + epb; if (e1 > E) e1 = E;
    for (long long e = e0 + t; e < e1; e += 512) {
        int d = f64 ? (int)((const long long*)edges)[E + e] : ((const int*)edges)[E + e];
        atomicAdd(&cnt[d >> BSHIFT], 1);
    }
    __syncthreads();
    for (int b = t; b < nbuckets; b += 512) partial[b * nblk + i] = cnt[b];
}

// ---- (B) per-bucket exclusive scan over blocks; emits bucket totals ----
__global__ __launch_bounds__(256) void k_scanB(int* partial, int nblk, int* totals) {
    __shared__ int tmp[256];
    int b = blockIdx.x, t = threadIdx.x;
    int v = (t < nblk) ? partial[b * nblk + t] : 0;
    tmp[t] = v;
    __syncthreads();
    for (int off = 1; off < 256; off <<= 1) {
        int a = (t >= off) ? tmp[t - off] : 0;
        __syncthreads();
        tmp[t] += a;
        __syncthreads();
    }
    if (t < nblk) partial[b * nblk + t] = tmp[t] - v;  // exclusive over blocks
    if (t == 255) totals[b] = tmp[255];
}

// ---- (C) bucket-level exclusive scan: base = exclusive(totals) ----
__global__ __launch_bounds__(1024) void k_scan(const int* __restrict__ totals, int nbuckets,
                                               int* base) {
    __shared__ int tmp[MAXB];
    int t = threadIdx.x;
    int v = (t < nbuckets) ? totals[t] : 0;
    tmp[t] = v;
    __syncthreads();
    for (int off = 1; off < MAXB; off <<= 1) {
        int a = (t >= off) ? tmp[t - off] : 0;
        __syncthreads();
        tmp[t] += a;
        __syncthreads();
    }
    if (t < nbuckets) base[t] = tmp[t] - v;
}

// ---- (D) place keys: LDS cursors seeded from base+partial; no global atomics ----
__global__ __launch_bounds__(512) void k_place(const void* edges, long long nn,
                                               long long E, long long epb,
                                               int nbuckets, int nblk,
                                               const int* __restrict__ base,
                                               const int* __restrict__ partial,
                                               unsigned int* keys) {
    __shared__ int cur[MAXB];
    int t = threadIdx.x;
    int i = blockIdx.x;
    for (int b = t; b < nbuckets; b += 512) cur[b] = base[b] + partial[b * nblk + i];
    __syncthreads();
    bool f64 = detect_f64(edges, nn);
    long long e0 = (long long)i * epb;
    long long e1 = e0 + epb; if (e1 > E) e1 = E;
    for (long long e = e0 + t; e < e1; e += 512) {
        int s, d;
        if (f64) {
            const long long* ee = (const long long*)edges;
            s = (int)ee[e]; d = (int)ee[E + e];
        } else {
            const int* ee = (const int*)edges;
            s = ee[e]; d = ee[E + e];
        }
        int pos = atomicAdd(&cur[d >> BSHIFT], 1);
        keys[pos] = (unsigned int)s | ((unsigned int)(d & (BNODES - 1)) << 17);
    }
}

// -------- per-bucket LDS counting sort -> node-exact CSR; fuses deg/dinv --------
__global__ __launch_bounds__(256) void k_sortdeg(unsigned int* keys,
                                                 const int* __restrict__ base,
                                                 const int* __restrict__ totals,
                                                 int* rowstart, int* counts,
                                                 float* dinv, int n,
                                                 unsigned int* scratch) {
    __shared__ unsigned int kbuf[SORTCAP];
    __shared__ int hist[BNODES];
    __shared__ int cur[BNODES];
    int t = threadIdx.x;
    int bk = blockIdx.x;
    int st = base[bk], c = totals[bk];
    if (t < BNODES) hist[t] = 0;
    __syncthreads();
    bool fits = (c <= SORTCAP);
    if (fits) {
        for (int i = t; i < c; i += 256) {
            unsigned int k = keys[st + i];
            kbuf[i] = k;
            atomicAdd(&hist[k >> 17], 1);
        }
    } else {  // statistically never for random edges; correct fallback via global scratch
        for (int i = t; i < c; i += 256) {
            unsigned int k = keys[st + i];
            scratch[st + i] = k;
            atomicAdd(&hist[k >> 17], 1);
        }
    }
    __syncthreads();
    if (t < 64) {  // wave 0: scan 64 counters
        int v = hist[t];
        int incl = v;
        for (int o = 1; o < 64; o <<= 1) {
            int other = __shfl_up(incl, o, 64);
            if (t >= o) incl += other;
        }
        int ex = incl - v;
        cur[t] = ex;
        int node = bk * BNODES + t;
        if (node < n) {
            rowstart[node] = st + ex;
            counts[node] = v;
            dinv[node] = rsqrtf((float)v + 1.0f);
        }
    }
    __syncthreads();
    if (fits) {
        for (int i = t; i < c; i += 256) {
            unsigned int k = kbuf[i];
            int pos = atomicAdd(&cur[k >> 17], 1);
            keys[st + pos] = k & 0x1FFFFu;
        }
    } else {
        for (int i = t; i < c; i += 256) {
            unsigned int k = scratch[st + i];
            int pos = atomicAdd(&cur[k >> 17], 1);
            keys[st + pos] = k & 0x1FFFFu;
        }
    }
}

// -------- GEMM1: h1b[n,64](bf16) = dinv * (x[n,64] @ W1[64,64]) --------
__global__ __launch_bounds__(256) void k_gemm1(const float* __restrict__ x,
                                               const float* __restrict__ W,
                                               const float* __restrict__ dinv,
                                               unsigned short* __restrict__ h) {
    __shared__ float Ws[64][64];
    __shared__ float xs[16][64];
    int t = threadIdx.x;
    for (int i = t; i < 64 * 64; i += 256) Ws[i >> 6][i & 63] = W[i];
    long long row0 = (long long)blockIdx.x * 16;
    ((float4*)xs)[t] = ((const float4*)(x + row0 * 64))[t];
    __syncthreads();
    int r = t >> 4, c0 = (t & 15) * 4;
    float4 acc = {0.f, 0.f, 0.f, 0.f};
#pragma unroll
    for (int k = 0; k < 64; ++k) {
        float xv = xs[r][k];
        float4 wv = *((const float4*)&Ws[k][c0]);
        acc.x += xv * wv.x; acc.y += xv * wv.y;
        acc.z += xv * wv.z; acc.w += xv * wv.w;
    }
    float di = dinv[row0 + r];
    ushort4 pk;
    pk.x = bf16enc(di * acc.x);
    pk.y = bf16enc(di * acc.y);
    pk.z = bf16enc(di * acc.z);
    pk.w = bf16enc(di * acc.w);
    *((ushort4*)(h + (row0 + r) * 64 + c0)) = pk;
}

// ------- CSR aggregation, 64 feats (bf16, 2-wide) + FUSED GEMM2 epilogue -------
// Gather phase (r10-measured best): 32 lanes x uint cover a 128B row; half-waves
// take even/odd edges. Epilogue: relu'd row (2 feats/lane, both halves) is
// shuffle-transposed into a 64x16 dot with LDS-staged W2, emitting the bf16
// h2 row directly (replaces the separate k_gemm2 kernel + out1 buffer).
__global__ __launch_bounds__(256) void k_agg64(const int* __restrict__ rowstart,
                                               const int* __restrict__ counts,
                                               const unsigned int* __restrict__ srcs,
                                               const unsigned int* __restrict__ hb2,
                                               const float* __restrict__ dinv,
                                               const float* __restrict__ b,
                                               const float* __restrict__ W2,
                                               unsigned short* __restrict__ h2b, int n) {
    __shared__ float W2s[64 * 16];
    int t = threadIdx.x;
    for (int i = t; i < 64 * 16 / 4; i += 256) ((float4*)W2s)[i] = ((const float4*)W2)[i];
    __syncthreads();  // before any divergence; all waves hit this immediately

    int d = (blockIdx.x * 256 + t) >> 6;
    if (d >= n) return;
    int lane = t & 63;
    int half = lane >> 5;     // 0: even edges, 1: odd edges
    int fl = lane & 31;       // feature-pair index (features 2fl, 2fl+1)
    float ax = 0.f, ay = 0.f;
    if (half == 0) {          // self-loop counted once
        unsigned int u = hb2[(long long)d * 32 + fl];
        ax = bf16lo(u); ay = bf16hi(u);
    }
    int start = rowstart[d];
    int cnt = counts[d];
    int k = 0;
    for (; k + 8 <= cnt; k += 8) {
        unsigned int s0 = srcs[start + k + half];
        unsigned int s1 = srcs[start + k + 2 + half];
        unsigned int s2 = srcs[start + k + 4 + half];
        unsigned int s3 = srcs[start + k + 6 + half];
        unsigned int u0 = hb2[(long long)s0 * 32 + fl];
        unsigned int u1 = hb2[(long long)s1 * 32 + fl];
        unsigned int u2 = hb2[(long long)s2 * 32 + fl];
        unsigned int u3 = hb2[(long long)s3 * 32 + fl];
        ax += bf16lo(u0); ay += bf16hi(u0);
        ax += bf16lo(u1); ay += bf16hi(u1);
        ax += bf16lo(u2); ay += bf16hi(u2);
        ax += bf16lo(u3); ay += bf16hi(u3);
    }
    for (; k < cnt; k += 2) {
        int idx = k + half;
        unsigned int u0 = 0;
        if (idx < cnt) u0 = hb2[(long long)srcs[start + idx] * 32 + fl];
        ax += bf16lo(u0); ay += bf16hi(u0);
    }
    // combine even/odd halves; BOTH halves now hold row totals
    ax += __shfl_xor(ax, 32);
    ay += __shfl_xor(ay, 32);
    float di = dinv[d];
    float2 bb = ((const float2*)b)[fl];
    float ox = fmaxf(di * ax + bb.x, 0.f);   // relu'd feat 2fl
    float oy = fmaxf(di * ay + bb.y, 0.f);   // relu'd feat 2fl+1

    // fused GEMM2: lane computes partial dot for col c over its k-quarter
    int c = lane & 15, q = lane >> 4;
    float acc = 0.f;
#pragma unroll
    for (int j = 0; j < 16; ++j) {
        int kk = q * 16 + j;
        int srcl = kk >> 1;                       // lane holding feat kk
        float fv = (kk & 1) ? __shfl(oy, srcl) : __shfl(ox, srcl);
        acc += fv * W2s[kk * 16 + c];
    }
    acc += __shfl_xor(acc, 16);
    acc += __shfl_xor(acc, 32);
    if (lane < 16) h2b[(long long)d * 16 + c] = bf16enc(di * acc);
}

// ------- CSR aggregation, 16 feats (bf16 h) + fused log_softmax ----------------
__global__ __launch_bounds__(256) void k_agg16(const int* __restrict__ rowstart,
                                               const int* __restrict__ counts,
                                               const unsigned int* __restrict__ srcs,
                                               const unsigned short* __restrict__ hb,
                                               const float* __restrict__ dinv,
                                               const float* __restrict__ b,
                                               float* __restrict__ out, int n) {
    int g = (blockIdx.x * 256 + threadIdx.x) >> 4;
    if (g >= n) return;
    int f = threadIdx.x & 15;
    long long rb = (long long)g * 16;
    float acc = bf16dec(hb[rb + f]);
    int start = rowstart[g];
    int cnt = counts[g];
    int k = 0;
    for (; k + 8 <= cnt; k += 8) {
        unsigned int s0 = srcs[start + k];
        unsigned int s1 = srcs[start + k + 1];
        unsigned int s2 = srcs[start + k + 2];
        unsigned int s3 = srcs[start + k + 3];
        unsigned int s4 = srcs[start + k + 4];
        unsigned int s5 = srcs[start + k + 5];
        unsigned int s6 = srcs[start + k + 6];
        unsigned int s7 = srcs[start + k + 7];
        unsigned short u0 = hb[(long long)s0 * 16 + f];
        unsigned short u1 = hb[(long long)s1 * 16 + f];
        unsigned short u2 = hb[(long long)s2 * 16 + f];
        unsigned short u3 = hb[(long long)s3 * 16 + f];
        unsigned short u4 = hb[(long long)s4 * 16 + f];
        unsigned short u5 = hb[(long long)s5 * 16 + f];
        unsigned short u6 = hb[(long long)s6 * 16 + f];
        unsigned short u7 = hb[(long long)s7 * 16 + f];
        acc += bf16dec(u0); acc += bf16dec(u1); acc += bf16dec(u2); acc += bf16dec(u3);
        acc += bf16dec(u4); acc += bf16dec(u5); acc += bf16dec(u6); acc += bf16dec(u7);
    }
    for (; k < cnt; ++k) acc += bf16dec(hb[(long long)srcs[start + k] * 16 + f]);
    float v = dinv[g] * acc + b[f];
    float m = v;
#pragma unroll
    for (int o = 8; o >= 1; o >>= 1) m = fmaxf(m, __shfl_xor(m, o, 16));
    float ex = __expf(v - m);
#pragma unroll
    for (int o = 8; o >= 1; o >>= 1) ex += __shfl_xor(ex, o, 16);
    out[rb + f] = (v - m) - __logf(ex);
}

extern "C" void kernel_launch(void* const* d_in, const int* in_sizes, int n_in,
                              void* d_out, int out_size, void* d_ws, size_t ws_size,
                              hipStream_t stream) {
    const float* x  = (const float*)d_in[0];
    const void*  ei = d_in[1];
    const float* W1 = (const float*)d_in[2];
    const float* b1 = (const float*)d_in[3];
    const float* W2 = (const float*)d_in[4];
    const float* b2 = (const float*)d_in[5];

    long long dh  = in_sizes[3];                 // 64
    long long din = in_sizes[2] / dh;            // 64
    long long n   = in_sizes[0] / din;           // 50000
    long long E   = (long long)in_sizes[1] / 2;  // 1.6M
    int nbuckets  = (int)((n + BNODES - 1) >> BSHIFT);  // 782

    // slice size: 512 threads x ~16 edges; keep block count <= 256 (k_scanB width)
    long long epb = 8192;
    while ((E + epb - 1) / epb > 256) epb <<= 1;
    int nblk = (int)((E + epb - 1) / epb);       // 196 for E=1.6M

    char* ws = (char*)d_ws;
    auto alloc = [&](size_t bytes) { void* p = ws; ws += (bytes + 255) & ~255ULL; return p; };
    int*   totals   = (int*)alloc(nbuckets * 4);
    int*   base     = (int*)alloc(nbuckets * 4);
    int*   rowstart = (int*)alloc(n * 4);
    int*   counts   = (int*)alloc(n * 4);
    float* dinv     = (float*)alloc(n * 4);
    int*   partial  = (int*)alloc((size_t)nbuckets * nblk * 4);
    unsigned int* keys = (unsigned int*)alloc(E * 4);
    unsigned short* h1b  = (unsigned short*)alloc(n * 64 * 2);
    unsigned short* h2b  = (unsigned short*)alloc(n * 16 * 2);
    // h1b is written only after sortdeg completes; before then its space doubles
    // as the (statistically never used) big-bucket sort scratch (E*4 <= n*64*2).
    unsigned int* sort_scratch = (unsigned int*)h1b;

    float* out = (float*)d_out;

    // binning: hist -> per-bucket block scan -> bucket scan -> place (no global atomics)
    k_hist<<<nblk, 512, 0, stream>>>(ei, n, E, epb, nbuckets, nblk, partial);
    k_scanB<<<nbuckets, 256, 0, stream>>>(partial, nblk, totals);
    k_scan<<<1, 1024, 0, stream>>>(totals, nbuckets, base);
    k_place<<<nblk, 512, 0, stream>>>(ei, n, E, epb, nbuckets, nblk, base, partial, keys);
    k_sortdeg<<<nbuckets, 256, 0, stream>>>(keys, base, totals, rowstart, counts,
                                            dinv, (int)n, sort_scratch);

    // layer 1 (+ fused layer-2 GEMM in agg64 epilogue)
    k_gemm1<<<(int)(n / 16), 256, 0, stream>>>(x, W1, dinv, h1b);
    k_agg64<<<(int)((n * 64 + 255) / 256), 256, 0, stream>>>(
        rowstart, counts, keys, (const unsigned int*)h1b, dinv, b1, W2, h2b, (int)n);

    // layer 2 aggregation + log_softmax
    k_agg16<<<(int)((n * 16 + 255) / 256), 256, 0, stream>>>(
        rowstart, counts, keys, h2b, dinv, b2, out, (int)n);
}

// Round 13
// 116.901 us; speedup vs baseline: 1.1449x; 1.0097x over previous
//
#include <hip/hip_runtime.h>
#include <hip/hip_bf16.h>
#include <math.h>

// bucket = 64 consecutive dst nodes. key packs (dlow<<17 | src), valid for n < 131072.
#define BSHIFT 6
#define BNODES 64
#define MAXB 1024   // max buckets supported by single-block scan (n <= 65536)
#define SORTCAP 4096

// ---------------- inline dtype detection: int64 vs int32 edge_index ----------------
__device__ __forceinline__ bool detect_f64(const void* edges, long long nn) {
    const long long* e64 = (const long long*)edges;
    bool ok = true;
#pragma unroll
    for (int i = 0; i < 8; ++i) {
        long long v = e64[i];
        ok = ok && (v >= 0 && v < nn);
    }
    return ok;
}

__device__ __forceinline__ float bf16lo(unsigned int u) {
    return __uint_as_float(u << 16);
}
__device__ __forceinline__ float bf16hi(unsigned int u) {
    return __uint_as_float(u & 0xFFFF0000u);
}
__device__ __forceinline__ float bf16dec(unsigned short u) {
    return __uint_as_float(((unsigned int)u) << 16);
}
__device__ __forceinline__ unsigned short bf16enc(float f) {
    __hip_bfloat16 h = __float2bfloat16(f);
    return *reinterpret_cast<unsigned short*>(&h);
}

// ---- (A) per-block-slice histogram -> partial[b*nblk + i] (plain stores) ----
__global__ __launch_bounds__(512) void k_hist(const void* edges, long long nn,
                                              long long E, long long epb,
                                              int nbuckets, int nblk, int* partial) {
    __shared__ int cnt[MAXB];
    int t = threadIdx.x;
    int i = blockIdx.x;
    for (int b = t; b < nbuckets; b += 512) cnt[b] = 0;
    __syncthreads();
    bool f64 = detect_f64(edges, nn);
    long long e0 = (long long)i * epb;
    long long e1 = e0 + epb; if (e1 > E) e1 = E;
    for (long long e = e0 + t; e < e1; e += 512) {
        int d = f64 ? (int)((const long long*)edges)[E + e] : ((const int*)edges)[E + e];
        atomicAdd(&cnt[d >> BSHIFT], 1);
    }
    __syncthreads();
    for (int b = t; b < nbuckets; b += 512) partial[b * nblk + i] = cnt[b];
}

// ---- (B) per-bucket exclusive scan over blocks; emits bucket totals ----
__global__ __launch_bounds__(256) void k_scanB(int* partial, int nblk, int* totals) {
    __shared__ int tmp[256];
    int b = blockIdx.x, t = threadIdx.x;
    int v = (t < nblk) ? partial[b * nblk + t] : 0;
    tmp[t] = v;
    __syncthreads();
    for (int off = 1; off < 256; off <<= 1) {
        int a = (t >= off) ? tmp[t - off] : 0;
        __syncthreads();
        tmp[t] += a;
        __syncthreads();
    }
    if (t < nblk) partial[b * nblk + t] = tmp[t] - v;  // exclusive over blocks
    if (t == 255) totals[b] = tmp[255];
}

// ---- (C) bucket-level exclusive scan: base = exclusive(totals) ----
__global__ __launch_bounds__(1024) void k_scan(const int* __restrict__ totals, int nbuckets,
                                               int* base) {
    __shared__ int tmp[MAXB];
    int t = threadIdx.x;
    int v = (t < nbuckets) ? totals[t] : 0;
    tmp[t] = v;
    __syncthreads();
    for (int off = 1; off < MAXB; off <<= 1) {
        int a = (t >= off) ? tmp[t - off] : 0;
        __syncthreads();
        tmp[t] += a;
        __syncthreads();
    }
    if (t < nbuckets) base[t] = tmp[t] - v;
}

// ---- (D) place keys: LDS cursors seeded from base+partial; no global atomics ----
__global__ __launch_bounds__(512) void k_place(const void* edges, long long nn,
                                               long long E, long long epb,
                                               int nbuckets, int nblk,
                                               const int* __restrict__ base,
                                               const int* __restrict__ partial,
                                               unsigned int* keys) {
    __shared__ int cur[MAXB];
    int t = threadIdx.x;
    int i = blockIdx.x;
    for (int b = t; b < nbuckets; b += 512) cur[b] = base[b] + partial[b * nblk + i];
    __syncthreads();
    bool f64 = detect_f64(edges, nn);
    long long e0 = (long long)i * epb;
    long long e1 = e0 + epb; if (e1 > E) e1 = E;
    for (long long e = e0 + t; e < e1; e += 512) {
        int s, d;
        if (f64) {
            const long long* ee = (const long long*)edges;
            s = (int)ee[e]; d = (int)ee[E + e];
        } else {
            const int* ee = (const int*)edges;
            s = ee[e]; d = ee[E + e];
        }
        int pos = atomicAdd(&cur[d >> BSHIFT], 1);
        keys[pos] = (unsigned int)s | ((unsigned int)(d & (BNODES - 1)) << 17);
    }
}

// -------- per-bucket LDS counting sort -> node-exact CSR; fuses deg/dinv --------
__global__ __launch_bounds__(256) void k_sortdeg(unsigned int* keys,
                                                 const int* __restrict__ base,
                                                 const int* __restrict__ totals,
                                                 int* rowstart, int* counts,
                                                 float* dinv, int n,
                                                 unsigned int* scratch) {
    __shared__ unsigned int kbuf[SORTCAP];
    __shared__ int hist[BNODES];
    __shared__ int cur[BNODES];
    int t = threadIdx.x;
    int bk = blockIdx.x;
    int st = base[bk], c = totals[bk];
    if (t < BNODES) hist[t] = 0;
    __syncthreads();
    bool fits = (c <= SORTCAP);
    if (fits) {
        for (int i = t; i < c; i += 256) {
            unsigned int k = keys[st + i];
            kbuf[i] = k;
            atomicAdd(&hist[k >> 17], 1);
        }
    } else {  // statistically never for random edges; correct fallback via global scratch
        for (int i = t; i < c; i += 256) {
            unsigned int k = keys[st + i];
            scratch[st + i] = k;
            atomicAdd(&hist[k >> 17], 1);
        }
    }
    __syncthreads();
    if (t < 64) {  // wave 0: scan 64 counters
        int v = hist[t];
        int incl = v;
        for (int o = 1; o < 64; o <<= 1) {
            int other = __shfl_up(incl, o, 64);
            if (t >= o) incl += other;
        }
        int ex = incl - v;
        cur[t] = ex;
        int node = bk * BNODES + t;
        if (node < n) {
            rowstart[node] = st + ex;
            counts[node] = v;
            dinv[node] = rsqrtf((float)v + 1.0f);
        }
    }
    __syncthreads();
    if (fits) {
        for (int i = t; i < c; i += 256) {
            unsigned int k = kbuf[i];
            int pos = atomicAdd(&cur[k >> 17], 1);
            keys[st + pos] = k & 0x1FFFFu;
        }
    } else {
        for (int i = t; i < c; i += 256) {
            unsigned int k = scratch[st + i];
            int pos = atomicAdd(&cur[k >> 17], 1);
            keys[st + pos] = k & 0x1FFFFu;
        }
    }
}

// -------- GEMM1: h1b[n,64](bf16) = dinv * (x[n,64] @ W1[64,64]) --------
__global__ __launch_bounds__(256) void k_gemm1(const float* __restrict__ x,
                                               const float* __restrict__ W,
                                               const float* __restrict__ dinv,
                                               unsigned short* __restrict__ h) {
    __shared__ float Ws[64][64];
    __shared__ float xs[16][64];
    int t = threadIdx.x;
    for (int i = t; i < 64 * 64; i += 256) Ws[i >> 6][i & 63] = W[i];
    long long row0 = (long long)blockIdx.x * 16;
    ((float4*)xs)[t] = ((const float4*)(x + row0 * 64))[t];
    __syncthreads();
    int r = t >> 4, c0 = (t & 15) * 4;
    float4 acc = {0.f, 0.f, 0.f, 0.f};
#pragma unroll
    for (int k = 0; k < 64; ++k) {
        float xv = xs[r][k];
        float4 wv = *((const float4*)&Ws[k][c0]);
        acc.x += xv * wv.x; acc.y += xv * wv.y;
        acc.z += xv * wv.z; acc.w += xv * wv.w;
    }
    float di = dinv[row0 + r];
    ushort4 pk;
    pk.x = bf16enc(di * acc.x);
    pk.y = bf16enc(di * acc.y);
    pk.z = bf16enc(di * acc.z);
    pk.w = bf16enc(di * acc.w);
    *((ushort4*)(h + (row0 + r) * 64 + c0)) = pk;
}

// ------- CSR aggregation, 64 feats (bf16, 2-wide) + FUSED GEMM2 epilogue -------
// Gather: 32 lanes x uint cover a 128B row; half-waves take even/odd edges.
// 32-bit gather indices -> saddr global_load form (no 64-bit VGPR addr math).
// Epilogue: relu'd row is shuffle-transposed into a 64x16 dot with LDS-staged
// W2 (padded stride 17 to break bank conflicts), emitting bf16 h2 directly.
__global__ __launch_bounds__(256) void k_agg64(const int* __restrict__ rowstart,
                                               const int* __restrict__ counts,
                                               const unsigned int* __restrict__ srcs,
                                               const unsigned int* __restrict__ hb2,
                                               const float* __restrict__ dinv,
                                               const float* __restrict__ b,
                                               const float* __restrict__ W2,
                                               unsigned short* __restrict__ h2b, int n) {
    __shared__ float W2s[64 * 17];
    int t = threadIdx.x;
    for (int i = t; i < 64 * 16; i += 256) W2s[(i >> 4) * 17 + (i & 15)] = W2[i];
    __syncthreads();  // before any divergence; all waves hit this immediately

    int d = (blockIdx.x * 256 + t) >> 6;
    if (d >= n) return;
    int lane = t & 63;
    unsigned int half = lane >> 5;   // 0: even edges, 1: odd edges
    unsigned int fl = lane & 31;     // feature-pair index (features 2fl, 2fl+1)
    float ax = 0.f, ay = 0.f;
    if (half == 0) {                 // self-loop counted once
        unsigned int u = hb2[(unsigned int)d * 32u + fl];
        ax = bf16lo(u); ay = bf16hi(u);
    }
    int start = rowstart[d];
    int cnt = counts[d];
    int k = 0;
    for (; k + 16 <= cnt; k += 16) {
        unsigned int s0 = srcs[start + k + half];
        unsigned int s1 = srcs[start + k + 2 + half];
        unsigned int s2 = srcs[start + k + 4 + half];
        unsigned int s3 = srcs[start + k + 6 + half];
        unsigned int s4 = srcs[start + k + 8 + half];
        unsigned int s5 = srcs[start + k + 10 + half];
        unsigned int s6 = srcs[start + k + 12 + half];
        unsigned int s7 = srcs[start + k + 14 + half];
        unsigned int u0 = hb2[s0 * 32u + fl];
        unsigned int u1 = hb2[s1 * 32u + fl];
        unsigned int u2 = hb2[s2 * 32u + fl];
        unsigned int u3 = hb2[s3 * 32u + fl];
        unsigned int u4 = hb2[s4 * 32u + fl];
        unsigned int u5 = hb2[s5 * 32u + fl];
        unsigned int u6 = hb2[s6 * 32u + fl];
        unsigned int u7 = hb2[s7 * 32u + fl];
        ax += bf16lo(u0); ay += bf16hi(u0);
        ax += bf16lo(u1); ay += bf16hi(u1);
        ax += bf16lo(u2); ay += bf16hi(u2);
        ax += bf16lo(u3); ay += bf16hi(u3);
        ax += bf16lo(u4); ay += bf16hi(u4);
        ax += bf16lo(u5); ay += bf16hi(u5);
        ax += bf16lo(u6); ay += bf16hi(u6);
        ax += bf16lo(u7); ay += bf16hi(u7);
    }
    for (; k + 8 <= cnt; k += 8) {
        unsigned int s0 = srcs[start + k + half];
        unsigned int s1 = srcs[start + k + 2 + half];
        unsigned int s2 = srcs[start + k + 4 + half];
        unsigned int s3 = srcs[start + k + 6 + half];
        unsigned int u0 = hb2[s0 * 32u + fl];
        unsigned int u1 = hb2[s1 * 32u + fl];
        unsigned int u2 = hb2[s2 * 32u + fl];
        unsigned int u3 = hb2[s3 * 32u + fl];
        ax += bf16lo(u0); ay += bf16hi(u0);
        ax += bf16lo(u1); ay += bf16hi(u1);
        ax += bf16lo(u2); ay += bf16hi(u2);
        ax += bf16lo(u3); ay += bf16hi(u3);
    }
    for (; k < cnt; k += 2) {
        int idx = k + (int)half;
        unsigned int u0 = 0;
        if (idx < cnt) u0 = hb2[srcs[start + idx] * 32u + fl];
        ax += bf16lo(u0); ay += bf16hi(u0);
    }
    // combine even/odd halves; BOTH halves now hold row totals
    ax += __shfl_xor(ax, 32);
    ay += __shfl_xor(ay, 32);
    float di = dinv[d];
    float2 bb = ((const float2*)b)[fl];
    float ox = fmaxf(di * ax + bb.x, 0.f);   // relu'd feat 2fl
    float oy = fmaxf(di * ay + bb.y, 0.f);   // relu'd feat 2fl+1

    // fused GEMM2: lane computes partial dot for col c over its k-quarter
    int c = lane & 15, q = lane >> 4;
    float acc = 0.f;
#pragma unroll
    for (int j = 0; j < 16; ++j) {
        int kk = q * 16 + j;
        int srcl = kk >> 1;                       // lane holding feat kk
        float fv = (kk & 1) ? __shfl(oy, srcl) : __shfl(ox, srcl);
        acc += fv * W2s[kk * 17 + c];
    }
    acc += __shfl_xor(acc, 16);
    acc += __shfl_xor(acc, 32);
    if (lane < 16) h2b[(unsigned int)d * 16u + c] = bf16enc(di * acc);
}

// ------- CSR aggregation, 16 feats (bf16 h) + fused log_softmax ----------------
__global__ __launch_bounds__(256) void k_agg16(const int* __restrict__ rowstart,
                                               const int* __restrict__ counts,
                                               const unsigned int* __restrict__ srcs,
                                               const unsigned short* __restrict__ hb,
                                               const float* __restrict__ dinv,
                                               const float* __restrict__ b,
                                               float* __restrict__ out, int n) {
    int g = (blockIdx.x * 256 + threadIdx.x) >> 4;
    if (g >= n) return;
    unsigned int f = threadIdx.x & 15;
    float acc = bf16dec(hb[(unsigned int)g * 16u + f]);
    int start = rowstart[g];
    int cnt = counts[g];
    int k = 0;
    for (; k + 8 <= cnt; k += 8) {
        unsigned int s0 = srcs[start + k];
        unsigned int s1 = srcs[start + k + 1];
        unsigned int s2 = srcs[start + k + 2];
        unsigned int s3 = srcs[start + k + 3];
        unsigned int s4 = srcs[start + k + 4];
        unsigned int s5 = srcs[start + k + 5];
        unsigned int s6 = srcs[start + k + 6];
        unsigned int s7 = srcs[start + k + 7];
        unsigned short u0 = hb[s0 * 16u + f];
        unsigned short u1 = hb[s1 * 16u + f];
        unsigned short u2 = hb[s2 * 16u + f];
        unsigned short u3 = hb[s3 * 16u + f];
        unsigned short u4 = hb[s4 * 16u + f];
        unsigned short u5 = hb[s5 * 16u + f];
        unsigned short u6 = hb[s6 * 16u + f];
        unsigned short u7 = hb[s7 * 16u + f];
        acc += bf16dec(u0); acc += bf16dec(u1); acc += bf16dec(u2); acc += bf16dec(u3);
        acc += bf16dec(u4); acc += bf16dec(u5); acc += bf16dec(u6); acc += bf16dec(u7);
    }
    for (; k < cnt; ++k) acc += bf16dec(hb[srcs[start + k] * 16u + f]);
    float v = dinv[g] * acc + b[f];
    float m = v;
#pragma unroll
    for (int o = 8; o >= 1; o >>= 1) m = fmaxf(m, __shfl_xor(m, o, 16));
    float ex = __expf(v - m);
#pragma unroll
    for (int o = 8; o >= 1; o >>= 1) ex += __shfl_xor(ex, o, 16);
    out[(unsigned int)g * 16u + f] = (v - m) - __logf(ex);
}

extern "C" void kernel_launch(void* const* d_in, const int* in_sizes, int n_in,
                              void* d_out, int out_size, void* d_ws, size_t ws_size,
                              hipStream_t stream) {
    const float* x  = (const float*)d_in[0];
    const void*  ei = d_in[1];
    const float* W1 = (const float*)d_in[2];
    const float* b1 = (const float*)d_in[3];
    const float* W2 = (const float*)d_in[4];
    const float* b2 = (const float*)d_in[5];

    long long dh  = in_sizes[3];                 // 64
    long long din = in_sizes[2] / dh;            // 64
    long long n   = in_sizes[0] / din;           // 50000
    long long E   = (long long)in_sizes[1] / 2;  // 1.6M
    int nbuckets  = (int)((n + BNODES - 1) >> BSHIFT);  // 782

    // slice size: 512 threads x ~16 edges; keep block count <= 256 (k_scanB width)
    long long epb = 8192;
    while ((E + epb - 1) / epb > 256) epb <<= 1;
    int nblk = (int)((E + epb - 1) / epb);       // 196 for E=1.6M

    char* ws = (char*)d_ws;
    auto alloc = [&](size_t bytes) { void* p = ws; ws += (bytes + 255) & ~255ULL; return p; };
    int*   totals   = (int*)alloc(nbuckets * 4);
    int*   base     = (int*)alloc(nbuckets * 4);
    int*   rowstart = (int*)alloc(n * 4);
    int*   counts   = (int*)alloc(n * 4);
    float* dinv     = (float*)alloc(n * 4);
    int*   partial  = (int*)alloc((size_t)nbuckets * nblk * 4);
    unsigned int* keys = (unsigned int*)alloc(E * 4);
    unsigned short* h1b  = (unsigned short*)alloc(n * 64 * 2);
    unsigned short* h2b  = (unsigned short*)alloc(n * 16 * 2);
    // h1b is written only after sortdeg completes; before then its space doubles
    // as the (statistically never used) big-bucket sort scratch (E*4 <= n*64*2).
    unsigned int* sort_scratch = (unsigned int*)h1b;

    float* out = (float*)d_out;

    // binning: hist -> per-bucket block scan -> bucket scan -> place (no global atomics)
    k_hist<<<nblk, 512, 0, stream>>>(ei, n, E, epb, nbuckets, nblk, partial);
    k_scanB<<<nbuckets, 256, 0, stream>>>(partial, nblk, totals);
    k_scan<<<1, 1024, 0, stream>>>(totals, nbuckets, base);
    k_place<<<nblk, 512, 0, stream>>>(ei, n, E, epb, nbuckets, nblk, base, partial, keys);
    k_sortdeg<<<nbuckets, 256, 0, stream>>>(keys, base, totals, rowstart, counts,
                                            dinv, (int)n, sort_scratch);

    // layer 1 (+ fused layer-2 GEMM in agg64 epilogue)
    k_gemm1<<<(int)(n / 16), 256, 0, stream>>>(x, W1, dinv, h1b);
    k_agg64<<<(int)((n * 64 + 255) / 256), 256, 0, stream>>>(
        rowstart, counts, keys, (const unsigned int*)h1b, dinv, b1, W2, h2b, (int)n);

    // layer 2 aggregation + log_softmax
    k_agg16<<<(int)((n * 16 + 255) / 256), 256, 0, stream>>>(
        rowstart, counts, keys, h2b, dinv, b2, out, (int)n);
}